// Round 2
// baseline (859.008 us; speedup 1.0000x reference)
//
#include <hip/hip_runtime.h>
#include <stdint.h>

// Fully-fused MLP: 1048576 x (64 -> 128 -> 128 -> 128 -> 128 -> 64)
// ReLU after all but last layer. fp32 in/out, bf16 MFMA compute (fp32 accum).
//
// LDS-FREE scheme. Activations stay transposed (features x batch) in MFMA
// fragments. Layer: H' = relu(W*H + b) with mfma_f32_16x16x32_bf16:
//   A = W   (m = out_feature, k = in_feature)   -> 16B contiguous row loads
//   B = H   (k = in_feature,  n = batch row = lane&15)
//   C/D: lane(q,c) holds (m = mt*16 + q*4 + reg, n = c)      [m89-verified]
//
// KEY TRICK: hidden-feature numbering is arbitrary. We permute the COLUMNS
// of w_hid/w_out at preconvert time by pi(f): (mt=f>>4, q=(f>>2)&3, r=f&3)
// -> (s=mt>>1)<<5 | q<<3 | (mt&1)<<2 | r. Under this renumbering, the
// C-layout quad sets {f:(f>>2)&3==q} coincide with the B-layout quad sets
// {g:(g>>3)&3==q}, so the next layer's B fragment s is simply
//   [relu(acc[2s][0..3]), relu(acc[2s+1][0..3])]  packed to bf16 —
// no LDS, no shuffles, no cross-lane movement between layers at all.

#define D_IN   64
#define D_HID  128
#define D_OUT  64
#define N_HID  3
#define NT     2                     // 16-row batch tiles per wave
#define WAVES  4                     // waves per block (256 threads)
#define ROWS_PER_WAVE  (NT * 16)     // 32
#define ROWS_PER_BLOCK (WAVES * ROWS_PER_WAVE)  // 128

typedef __attribute__((ext_vector_type(8))) short  short8;   // 8 x bf16
typedef __attribute__((ext_vector_type(4))) float  floatx4;  // MFMA C/D

__device__ __forceinline__ unsigned int bfround(unsigned int u) {
  return u + 0x7fffu + ((u >> 16) & 1u);  // fp32 -> bf16 RNE (top 16 bits)
}
__device__ __forceinline__ unsigned int pack2bf(float lo, float hi) {
  unsigned int ulo = bfround(__float_as_uint(lo)) >> 16;
  unsigned int uhi = bfround(__float_as_uint(hi)) & 0xffff0000u;
  return ulo | uhi;
}
// frag s = [relu(lo4[0..3]) | relu(hi4[0..3])] as bf16
__device__ __forceinline__ short8 pack_relu8(floatx4 lo4, floatx4 hi4) {
  union { short8 s8; unsigned int u[4]; } ub;
  ub.u[0] = pack2bf(fmaxf(lo4[0], 0.f), fmaxf(lo4[1], 0.f));
  ub.u[1] = pack2bf(fmaxf(lo4[2], 0.f), fmaxf(lo4[3], 0.f));
  ub.u[2] = pack2bf(fmaxf(hi4[0], 0.f), fmaxf(hi4[1], 0.f));
  ub.u[3] = pack2bf(fmaxf(hi4[2], 0.f), fmaxf(hi4[3], 0.f));
  return ub.s8;
}
__device__ __forceinline__ floatx4 mfma16(short8 a, short8 b, floatx4 c) {
  return __builtin_amdgcn_mfma_f32_16x16x32_bf16(a, b, c, 0, 0, 0);
}

// ---- pre-pass: fp32 weights -> bf16, with column permutation -------------
#define W_IN_ELEMS  (D_HID * D_IN)                   // 8192
#define W_HID_ELEMS (N_HID * D_HID * D_HID)          // 49152
#define W_OUT_ELEMS (D_OUT * D_HID)                  // 8192
#define W_TOTAL     (W_IN_ELEMS + W_HID_ELEMS + W_OUT_ELEMS)  // 65536

// stored column g reads original column p(g) = pi^{-1}(g)
__device__ __forceinline__ int permcol(int g) {
  return ((g >> 5) << 5) + (((g >> 2) & 1) << 4) + (((g >> 3) & 3) << 2) + (g & 3);
}

__global__ void wconvert_kernel(const float* __restrict__ w_in,
                                const float* __restrict__ w_hid,
                                const float* __restrict__ w_out,
                                unsigned short* __restrict__ wbf) {
  const int i = blockIdx.x * 256 + threadIdx.x;
  float v;
  if (i < W_IN_ELEMS) {
    v = w_in[i];  // layer-0 consumes raw x: no permutation
  } else if (i < W_IN_ELEMS + W_HID_ELEMS) {
    const int idx = i - W_IN_ELEMS;
    const int l = idx >> 14, rem = idx & 16383;
    const int o = rem >> 7, g = rem & 127;
    v = w_hid[(l << 14) + (o << 7) + permcol(g)];
  } else {
    const int idx = i - W_IN_ELEMS - W_HID_ELEMS;
    const int o = idx >> 7, g = idx & 127;
    v = w_out[(o << 7) + permcol(g)];
  }
  wbf[i] = (unsigned short)(bfround(__float_as_uint(v)) >> 16);
}

// ---- main fused kernel (no LDS, no __syncthreads) ------------------------
__global__ __launch_bounds__(WAVES * 64, 4) void mlp_kernel(
    const float* __restrict__ x,
    const unsigned short* __restrict__ wbf,
    const float* __restrict__ b_in,
    const float* __restrict__ b_hid,
    const float* __restrict__ b_out,
    float* __restrict__ out) {
  const int wv   = threadIdx.x >> 6;
  const int lane = threadIdx.x & 63;
  const int q    = lane >> 4;
  const int c    = lane & 15;
  const int rowbase = (blockIdx.x * WAVES + wv) * ROWS_PER_WAVE;

  const unsigned short* w0 = wbf;                             // [128][64]
  const unsigned short* wh = wbf + W_IN_ELEMS;                // [3][128][128]
  const unsigned short* wo = wbf + W_IN_ELEMS + W_HID_ELEMS;  // [64][128]

  // ---- layer 0: B-frags straight from x (K=64 -> 2 frags) ----
  short8 xf[NT][2];
#pragma unroll
  for (int nt = 0; nt < NT; ++nt) {
    const float* xr = x + (size_t)(rowbase + nt * 16 + c) * D_IN + q * 8;
#pragma unroll
    for (int s = 0; s < 2; ++s) {
      floatx4 f0 = *(const floatx4*)(xr + s * 32);
      floatx4 f1 = *(const floatx4*)(xr + s * 32 + 4);
      union { short8 s8; unsigned int u[4]; } ub;
      ub.u[0] = pack2bf(f0[0], f0[1]);
      ub.u[1] = pack2bf(f0[2], f0[3]);
      ub.u[2] = pack2bf(f1[0], f1[1]);
      ub.u[3] = pack2bf(f1[2], f1[3]);
      xf[nt][s] = ub.s8;
    }
  }

  short8 bfrag[NT][4];  // activation fragments, K=128

  // ---- layer 0 compute: M=128, K=64, ReLU -> bfrag ----
#pragma unroll
  for (int mt2 = 0; mt2 < 4; ++mt2) {
    floatx4 acc[NT][2];
#pragma unroll
    for (int h = 0; h < 2; ++h) {
      const int mt = mt2 * 2 + h;
      const unsigned short* wr = w0 + (mt * 16 + c) * D_IN + q * 8;
      short8 a0 = *(const short8*)(wr);
      short8 a1 = *(const short8*)(wr + 32);
      floatx4 bias = *(const floatx4*)(b_in + mt * 16 + q * 4);
#pragma unroll
      for (int nt = 0; nt < NT; ++nt) {
        floatx4 t = bias;
        t = mfma16(a0, xf[nt][0], t);
        t = mfma16(a1, xf[nt][1], t);
        acc[nt][h] = t;
      }
    }
#pragma unroll
    for (int nt = 0; nt < NT; ++nt)
      bfrag[nt][mt2] = pack_relu8(acc[nt][0], acc[nt][1]);
  }

  // ---- hidden layers: M=128, K=128, ReLU -> bfrag ----
#pragma unroll
  for (int l = 0; l < N_HID; ++l) {
    const unsigned short* wl = wh + l * (D_HID * D_HID);
    const float* bl = b_hid + l * D_HID;
    short8 nf[NT][4];
#pragma unroll
    for (int mt2 = 0; mt2 < 4; ++mt2) {
      floatx4 acc[NT][2];
#pragma unroll
      for (int h = 0; h < 2; ++h) {
        const int mt = mt2 * 2 + h;
        const unsigned short* wr = wl + (mt * 16 + c) * D_HID + q * 8;
        short8 a0 = *(const short8*)(wr);
        short8 a1 = *(const short8*)(wr + 32);
        short8 a2 = *(const short8*)(wr + 64);
        short8 a3 = *(const short8*)(wr + 96);
        floatx4 bias = *(const floatx4*)(bl + mt * 16 + q * 4);
#pragma unroll
        for (int nt = 0; nt < NT; ++nt) {
          floatx4 t = bias;
          t = mfma16(a0, bfrag[nt][0], t);
          t = mfma16(a1, bfrag[nt][1], t);
          t = mfma16(a2, bfrag[nt][2], t);
          t = mfma16(a3, bfrag[nt][3], t);
          acc[nt][h] = t;
        }
      }
#pragma unroll
      for (int nt = 0; nt < NT; ++nt)
        nf[nt][mt2] = pack_relu8(acc[nt][0], acc[nt][1]);
    }
#pragma unroll
    for (int nt = 0; nt < NT; ++nt)
#pragma unroll
      for (int s = 0; s < 4; ++s)
        bfrag[nt][s] = nf[nt][s];
  }

  // ---- output layer: M=64, K=128, no activation, direct store ----
#pragma unroll
  for (int mt = 0; mt < 4; ++mt) {
    const unsigned short* wr = wo + (mt * 16 + c) * D_HID + q * 8;
    short8 a0 = *(const short8*)(wr);
    short8 a1 = *(const short8*)(wr + 32);
    short8 a2 = *(const short8*)(wr + 64);
    short8 a3 = *(const short8*)(wr + 96);
    floatx4 bias = *(const floatx4*)(b_out + mt * 16 + q * 4);
#pragma unroll
    for (int nt = 0; nt < NT; ++nt) {
      floatx4 t = bias;
      t = mfma16(a0, bfrag[nt][0], t);
      t = mfma16(a1, bfrag[nt][1], t);
      t = mfma16(a2, bfrag[nt][2], t);
      t = mfma16(a3, bfrag[nt][3], t);
      // lane holds out[row = rowbase+nt*16+c][feat = mt*16 + q*4 + reg]
      *(floatx4*)(out + (size_t)(rowbase + nt * 16 + c) * D_OUT + mt * 16 + q * 4) = t;
    }
  }
}

extern "C" void kernel_launch(void* const* d_in, const int* in_sizes, int n_in,
                              void* d_out, int out_size, void* d_ws, size_t ws_size,
                              hipStream_t stream) {
  const float* x     = (const float*)d_in[0];
  const float* w_in  = (const float*)d_in[1];
  const float* b_in  = (const float*)d_in[2];
  const float* w_hid = (const float*)d_in[3];
  const float* b_hid = (const float*)d_in[4];
  const float* w_out = (const float*)d_in[5];
  const float* b_out = (const float*)d_in[6];
  float* out = (float*)d_out;
  unsigned short* wbf = (unsigned short*)d_ws;  // 131072 bytes used

  wconvert_kernel<<<W_TOTAL / 256, 256, 0, stream>>>(w_in, w_hid, w_out, wbf);

  const int N = in_sizes[0] / D_IN;            // 1048576
  const int blocks = N / ROWS_PER_BLOCK;       // 8192
  mlp_kernel<<<blocks, WAVES * 64, 0, stream>>>(x, wbf, b_in, b_hid, b_out, out);
}